// Round 1
// baseline (100.892 us; speedup 1.0000x reference)
//
#include <hip/hip_runtime.h>

// Problem constants (from reference): B=32, L=4096, D=128, N=5, V=128
constexpr int Bn = 32;
constexpr int Ln = 4096;
constexpr int Dn = 128;
constexpr int Vn = 128;
constexpr int N1 = 4;  // N - 1 context slots

typedef float vfloat4 __attribute__((ext_vector_type(4)));  // native vec for nontemporal builtins

// T layout (R7 change): [8 v-eighths][4 slots][128 tokens][16 v] fp32 = 256 KiB.
// Eighth-major so kernel B can stage one contiguous 32 KiB slice per block into LDS.
//
// Kernel A: T[e][k][t][vlo] = dot(emb[t], W[v, k*D:(k+1)*D]) (+ bias[v] for k==0),
// v = e*16 + vlo. grid: 4*128 = 512 blocks (one per (k,t)), block: 128 threads (v).
// NOTE (R4/R6 evidence): coalesced/transposed/shuffle-reduce variants measured
// neutral-to-worse; this latency-hidden form is fine at 512 blocks. Keep.
__global__ void build_table_kernel(const float* __restrict__ emb,
                                   const float* __restrict__ W,
                                   const float* __restrict__ bias,
                                   float* __restrict__ T) {
    const int kt = blockIdx.x;        // k*128 + t
    const int k  = kt >> 7;
    const int t  = kt & 127;
    const int v  = threadIdx.x;       // 0..127

    __shared__ float4 e[Dn / 4];
    if (threadIdx.x < Dn / 4) {
        e[threadIdx.x] = ((const float4*)(emb + t * Dn))[threadIdx.x];
    }
    __syncthreads();

    const float4* w = (const float4*)(W + (size_t)v * (Dn * N1) + k * Dn);
    float acc = (k == 0) ? bias[v] : 0.f;  // fold bias into slot-0 table
#pragma unroll
    for (int i = 0; i < Dn / 4; ++i) {
        float4 wv = w[i];
        float4 ev = e[i];
        acc += wv.x * ev.x + wv.y * ev.y + wv.z * ev.z + wv.w * ev.w;
    }
    // eighth-major layout: e = v>>4, vlo = v&15
    T[(size_t)(((v >> 4) * N1 + k) * Vn + t) * 16 + (v & 15)] = acc;
}

// Kernel B (R7 rewrite): out[b,j,v] = sum_k T'[k][x[b,j-4+k]][v], bias folded in T'[0].
// Each block owns one v-eighth (16 floats of v) and 1024 consecutive positions.
// Its 32 KiB slice of T is staged into LDS (rows padded 16->20 floats to scramble
// banks: row base bank = 4*(5r mod 8)), so the 4:1 gather traffic (268 MB total)
// hits LDS (~69 TB/s) instead of thrashing the 32 KiB L1 / L2. The kernel should
// then be bound by the 64 MiB nontemporal store stream (~11 us floor).
// 40 KiB LDS x 4 blocks/CU = 160 KiB, 4 x 512 thr = 2048 thr/CU (full occupancy).
constexpr int ROWS    = N1 * Vn;  // 512 table rows
constexpr int RSTRIDE = 20;       // padded floats per row (16 data + 4 pad)

__global__ void __launch_bounds__(512, 8)
ngram_logits_kernel(const int* __restrict__ x,
                    const float* __restrict__ T,
                    const float* __restrict__ bias,
                    float* __restrict__ out) {
    __shared__ float lds[ROWS * RSTRIDE];  // 40960 B

    const int e  = blockIdx.x & 7;   // v-eighth
    const int pb = blockIdx.x >> 3;  // position block, 0..127 (1024 positions each)

    // Stage this eighth of T: 512 rows x 16 floats = 2048 float4, coalesced.
    {
        const float4* src = (const float4*)(T + (size_t)e * (ROWS * 16));
        float4*       dst = (float4*)lds;
#pragma unroll
        for (int it = 0; it < 4; ++it) {
            const int f = it * 512 + threadIdx.x;  // float4 index 0..2047
            const int r = f >> 2;                  // row 0..511 (= k*128 + token)
            const int c = f & 3;                   // float4 within row
            dst[r * (RSTRIDE / 4) + c] = src[f];
        }
    }
    __syncthreads();

    const int vq = threadIdx.x & 3;   // float4 within the 16-float eighth
    const int gl = threadIdx.x >> 2;  // position group 0..127 within iteration
    const vfloat4* lv   = (const vfloat4*)lds;
    vfloat4*       outq = (vfloat4*)out;

#pragma unroll
    for (int it = 0; it < 2; ++it) {
        const int basepos = pb * 1024 + it * 512 + gl * 4;  // 4-aligned
        vfloat4*  ob      = outq + (size_t)basepos * 32 + e * 4 + vq;

        if ((basepos & (Ln - 1)) == 0) {
            // positions j=0..3 of a batch row: bias-only
            const vfloat4 bv = ((const vfloat4*)bias)[e * 4 + vq];
#pragma unroll
            for (int i = 0; i < 4; ++i)
                __builtin_nontemporal_store(bv, ob + i * 32);
            continue;
        }

        // token window w[0..6] = x[basepos-4 .. basepos+2]; both int4 loads aligned
        const int4 xa = *(const int4*)(x + basepos - 4);
        const int4 xb = *(const int4*)(x + basepos);
        const int  w[7] = {xa.x, xa.y, xa.z, xa.w, xb.x, xb.y, xb.z};

#pragma unroll
        for (int i = 0; i < 4; ++i) {
            // lds float4 index of row r = k*128 + tok is r*5 + vq
            vfloat4 a = lv[w[i] * 5 + vq];
#pragma unroll
            for (int k = 1; k < N1; ++k)
                a += lv[(k * Vn + w[i + k]) * 5 + vq];
            __builtin_nontemporal_store(a, ob + i * 32);  // R6: nt stores required
        }
    }
}

extern "C" void kernel_launch(void* const* d_in, const int* in_sizes, int n_in,
                              void* d_out, int out_size, void* d_ws, size_t ws_size,
                              hipStream_t stream) {
    const int*   x    = (const int*)d_in[0];    // (B, L) int32
    const float* emb  = (const float*)d_in[1];  // (V, D) fp32
    const float* W    = (const float*)d_in[2];  // (V, D*(N-1)) fp32
    const float* bias = (const float*)d_in[3];  // (V,) fp32
    float*       out  = (float*)d_out;          // (B, L, V) fp32
    float*       T    = (float*)d_ws;           // (8, 4, 128, 16) fp32 = 256 KiB

    build_table_kernel<<<N1 * Vn, Vn, 0, stream>>>(emb, W, bias, T);

    // 8 v-eighths x 128 position-blocks = 1024 blocks of 512 threads
    ngram_logits_kernel<<<1024, 512, 0, stream>>>(x, T, bias, out);
}

// Round 2
// 91.550 us; speedup vs baseline: 1.1020x; 1.1020x over previous
//
#include <hip/hip_runtime.h>

// Problem constants (from reference): B=32, L=4096, D=128, N=5, V=128
constexpr int Bn = 32;
constexpr int Ln = 4096;
constexpr int Dn = 128;
constexpr int Vn = 128;
constexpr int N1 = 4;  // N - 1 context slots

typedef float vfloat4 __attribute__((ext_vector_type(4)));  // native vec for nontemporal builtins

// T layout (R8): [4 v-quarters][4 slots][128 tokens][32 v] fp32 = 256 KiB.
// Quarter-major so kernel B stages one contiguous 64 KiB slice per block into LDS.
// R7 post-mortem: v-EIGHTH slices made wave stores 64 B scattered chunks (half an
// L2 line) -> ~2x write cost, +8 us. Quarter slices give 128 B full-line chunks.
//
// Kernel A: T[q][k][t][vlo] = dot(emb[t], W[v, k*D:(k+1)*D]) (+ bias[v] for k==0),
// v = q*32 + vlo. grid: 4*128 = 512 blocks (one per (k,t)), block: 128 threads (v).
// NOTE (R4/R6 evidence): coalesced/transposed/shuffle-reduce variants measured
// neutral-to-worse; this latency-hidden form is fine at 512 blocks. Keep.
__global__ void build_table_kernel(const float* __restrict__ emb,
                                   const float* __restrict__ W,
                                   const float* __restrict__ bias,
                                   float* __restrict__ T) {
    const int kt = blockIdx.x;        // k*128 + t
    const int k  = kt >> 7;
    const int t  = kt & 127;
    const int v  = threadIdx.x;       // 0..127

    __shared__ float4 e[Dn / 4];
    if (threadIdx.x < Dn / 4) {
        e[threadIdx.x] = ((const float4*)(emb + t * Dn))[threadIdx.x];
    }
    __syncthreads();

    const float4* w = (const float4*)(W + (size_t)v * (Dn * N1) + k * Dn);
    float acc = (k == 0) ? bias[v] : 0.f;  // fold bias into slot-0 table
#pragma unroll
    for (int i = 0; i < Dn / 4; ++i) {
        float4 wv = w[i];
        float4 ev = e[i];
        acc += wv.x * ev.x + wv.y * ev.y + wv.z * ev.z + wv.w * ev.w;
    }
    // quarter-major layout: q = v>>5, vlo = v&31; wave writes 128 B lines
    T[(size_t)(((v >> 5) * N1 + k) * Vn + t) * 32 + (v & 31)] = acc;
}

// Kernel B (R8): out[b,j,v] = sum_k T'[k][x[b,j-4+k]][v], bias folded into T'[0].
// Each block owns one v-quarter (32 floats) x 1024 consecutive positions.
// 64 KiB slice of T staged in LDS. Un-padded stride-32-float rows are provably
// bank-conflict-free for this access: lane (gl,vq) reads dword banks 4vq+{0..3}
// independent of the (random) token row, so each ds_read_b128 hits each bank
// exactly 8x = the 8-phase minimum. Wave stores: 8 x 128 B full L2 lines.
// 64 KiB x 2 blocks/CU = 128 KiB LDS, 16 waves/CU.
constexpr int ROWS = N1 * Vn;  // 512 table rows

__global__ void __launch_bounds__(512, 4)
ngram_logits_kernel(const int* __restrict__ x,
                    const float* __restrict__ T,
                    const float* __restrict__ bias,
                    float* __restrict__ out) {
    __shared__ float lds[ROWS * 32];  // 65536 B exactly

    const int q  = blockIdx.x & 3;   // v-quarter
    const int pb = blockIdx.x >> 2;  // position block, 0..127 (1024 positions each)

    // Stage this quarter of T: 512 rows x 32 floats = 4096 float4, coalesced, linear.
    {
        const float4* src = (const float4*)(T + (size_t)q * (ROWS * 32));
        float4*       dst = (float4*)lds;
#pragma unroll
        for (int it = 0; it < 8; ++it)
            dst[it * 512 + threadIdx.x] = src[it * 512 + threadIdx.x];
    }
    __syncthreads();

    const int vq = threadIdx.x & 7;   // float4 within the 32-float quarter
    const int gl = threadIdx.x >> 3;  // position group 0..63 within iteration
    const vfloat4* lv   = (const vfloat4*)lds;
    vfloat4*       outq = (vfloat4*)out;

#pragma unroll
    for (int it = 0; it < 4; ++it) {
        const int basepos = pb * 1024 + it * 256 + gl * 4;  // 4-aligned
        vfloat4*  ob      = outq + (size_t)basepos * 32 + q * 8 + vq;

        if ((basepos & (Ln - 1)) == 0) {
            // positions j=0..3 of a batch row: bias-only
            const vfloat4 bv = ((const vfloat4*)bias)[q * 8 + vq];
#pragma unroll
            for (int i = 0; i < 4; ++i)
                __builtin_nontemporal_store(bv, ob + i * 32);
            continue;
        }

        // token window w[0..6] = x[basepos-4 .. basepos+2]; both int4 loads aligned
        const int4 xa = *(const int4*)(x + basepos - 4);
        const int4 xb = *(const int4*)(x + basepos);
        const int  w[7] = {xa.x, xa.y, xa.z, xa.w, xb.x, xb.y, xb.z};

#pragma unroll
        for (int i = 0; i < 4; ++i) {
            // lds float4 index of row r = k*128 + tok is r*8 + vq
            vfloat4 a = lv[w[i] * 8 + vq];
#pragma unroll
            for (int k = 1; k < N1; ++k)
                a += lv[(k * Vn + w[i + k]) * 8 + vq];
            __builtin_nontemporal_store(a, ob + i * 32);  // R6: nt stores required
        }
    }
}

extern "C" void kernel_launch(void* const* d_in, const int* in_sizes, int n_in,
                              void* d_out, int out_size, void* d_ws, size_t ws_size,
                              hipStream_t stream) {
    const int*   x    = (const int*)d_in[0];    // (B, L) int32
    const float* emb  = (const float*)d_in[1];  // (V, D) fp32
    const float* W    = (const float*)d_in[2];  // (V, D*(N-1)) fp32
    const float* bias = (const float*)d_in[3];  // (V,) fp32
    float*       out  = (float*)d_out;          // (B, L, V) fp32
    float*       T    = (float*)d_ws;           // (4, 4, 128, 32) fp32 = 256 KiB

    build_table_kernel<<<N1 * Vn, Vn, 0, stream>>>(emb, W, bias, T);

    // 4 v-quarters x 128 position-blocks = 512 blocks of 512 threads
    ngram_logits_kernel<<<512, 512, 0, stream>>>(x, T, bias, out);
}